// Round 1
// 1432.776 us; speedup vs baseline: 1.1931x; 1.1931x over previous
//
#include <hip/hip_runtime.h>

// ROIMaskHead: x[1024,14,14,256] f32 -> 4x (conv3x3 256->256 + relu) ->
// conv_transpose 2x2 s2 + relu -> 1x1 conv ->80, out [1024,28,28,80] f32.
// All matmuls via mfma_f32_16x16x32_f16; activations/weights fp16, acc f32.

typedef _Float16 f16x8 __attribute__((ext_vector_type(8)));
typedef float    f32x4 __attribute__((ext_vector_type(4)));
typedef unsigned short u16;
typedef unsigned int   u32;

__device__ __forceinline__ u16 f2h(float f) {
  union { _Float16 h; u16 u; } c; c.h = (_Float16)f; return c.u;
}

__device__ __forceinline__ void store8(u16* dst, const u16* o) {
  uint4 v;
  v.x = (u32)o[0] | ((u32)o[1] << 16);
  v.y = (u32)o[2] | ((u32)o[3] << 16);
  v.z = (u32)o[4] | ((u32)o[5] << 16);
  v.w = (u32)o[6] | ((u32)o[7] << 16);
  *(uint4*)dst = v;
}

// ---------------------------------------------------------------------------
// Weight repack to MFMA B-fragment order (one coalesced dwordx4 per lane):
// WbP[l][tap][kc][cotile][lane=q*16+rr][j] = Wc[l][tap][ci=kc*32+q*8+j][co=ct*16+rr]
// WtP[ab][kc][ct][lane][j]                = Wt[3-ab][ci][co]   (spatial flip)
// WmP[kc][nt][lane][j]                    = Wm[ci][nc=nt*16+rr]
// ---------------------------------------------------------------------------
__global__ void prep_weights(const float* __restrict__ Wc, const float* __restrict__ Wt,
                             const float* __restrict__ Wm,
                             u16* __restrict__ WbP, u16* __restrict__ WtP,
                             u16* __restrict__ WmP) {
  int id = blockIdx.x * 256 + threadIdx.x;
  u16 o[8];
  if (id < 294912) {
    int li = id & 63; int rest = id >> 6;
    int ct = rest & 15; rest >>= 4;
    int kc = rest & 7;  rest >>= 3;          // rest = l*9+tap (0..35)
    int co  = ct * 16 + (li & 15);
    int ci0 = kc * 32 + (li >> 4) * 8;
#pragma unroll
    for (int j = 0; j < 8; j++) o[j] = f2h(Wc[(rest * 256 + ci0 + j) * 256 + co]);
    store8(&WbP[id * 8], o);
  } else if (id < 327680) {
    int id2 = id - 294912;
    int li = id2 & 63; int rest = id2 >> 6;
    int ct = rest & 15; rest >>= 4;
    int kc = rest & 7;  rest >>= 3;          // rest = ab (0..3)
    int srcq = 3 - rest;                     // kernel flip for conv_transpose
    int co  = ct * 16 + (li & 15);
    int ci0 = kc * 32 + (li >> 4) * 8;
#pragma unroll
    for (int j = 0; j < 8; j++) o[j] = f2h(Wt[(srcq * 256 + ci0 + j) * 256 + co]);
    store8(&WtP[id2 * 8], o);
  } else if (id < 330240) {
    int id3 = id - 327680;
    int li = id3 & 63; int rest = id3 >> 6;  // 0..39
    int kc = rest / 5, nt = rest % 5;
    int nc  = nt * 16 + (li & 15);
    int ci0 = kc * 32 + (li >> 4) * 8;
#pragma unroll
    for (int j = 0; j < 8; j++) o[j] = f2h(Wm[(ci0 + j) * 80 + nc]);
    store8(&WmP[id3 * 8], o);
  }
}

// ---------------------------------------------------------------------------
// conv3x3 SAME, 256->256, relu(x+b). One block = (roi, M-half of 112 px).
// 4 waves x (7 Mtiles x 4 Nfrags), K staged in 128-ci halves in LDS.
// This round: (a) windowed row staging (y=0: rows 0..8 = 126 px; y=1: rows
// 7..13 = 98 px) -- halves input refetch and staging time; (b) per-block tap
// rotation to de-hotspot L2 weight lines; (c) double-buffered B-fragment
// register prefetch (one (tap,kc) step ahead, incl. across the half barrier).
// ---------------------------------------------------------------------------
template <bool INF32>
__global__ __launch_bounds__(256, 2)
void conv_layer(const void* __restrict__ in_, const u16* __restrict__ WbP,
                const float* __restrict__ bc, u16* __restrict__ out, int layer) {
  __shared__ u16 sA[126 * 136 + 128];
  const int ZP = 126 * 136;
  const int tid = threadIdx.x;
  const int w = tid >> 6, lane = tid & 63, q = lane >> 4, r = lane & 15;
  const int roi = blockIdx.x, mhalf = blockIdx.y;
  const int mbase = mhalf * 112;
  const int base_px = mhalf ? 98 : 0;      // first staged pixel (row_lo * 14)
  const int n_px   = mhalf ? 98 : 126;     // staged pixel count (rows 7..13 / 0..8)
  const int rot = (blockIdx.x + mhalf) % 9;
  if (tid < 64) ((u32*)(sA + ZP))[tid] = 0u;

  int py[7], px[7];
#pragma unroll
  for (int mt = 0; mt < 7; mt++) {
    int p = mbase + mt * 16 + r;
    py[mt] = (p < 196) ? (p / 14) : 1000;   // 1000 => always invalid after +dy
    px[mt] = p % 14;
  }
  f32x4 acc[7][4];
#pragma unroll
  for (int mt = 0; mt < 7; mt++)
#pragma unroll
    for (int nf = 0; nf < 4; nf++) acc[mt][nf] = (f32x4){0.f, 0.f, 0.f, 0.f};

  const float* xin = (const float*)in_;
  const u16*   yin = (const u16*)in_;

  // per-(wave,lane) weight base; element offset for (tap,kc,nf):
  //   tap*65536 + kc*8192 + nf*512
  const u16* wb = WbP + (size_t)layer * 589824 + (w * 4) * 512 + lane * 8;

  f16x8 b0[4], b1[4];
#pragma unroll
  for (int nf = 0; nf < 4; nf++)
    b0[nf] = *(const f16x8*)&wb[rot * 65536 + nf * 512];   // (tap=rot, kc=0)

  for (int kh = 0; kh < 2; kh++) {
    if (kh) __syncthreads();
    if (INF32) {
      for (int c = tid; c < n_px * 32; c += 256) {
        int pix = c >> 5, c4 = (c & 31) * 4;
        const float4 v = *(const float4*)&xin[((size_t)roi * 196 + base_px + pix) * 256 + kh * 128 + c4];
        ushort4 h; h.x = f2h(v.x); h.y = f2h(v.y); h.z = f2h(v.z); h.w = f2h(v.w);
        *(ushort4*)&sA[pix * 136 + c4] = h;
      }
    } else {
      for (int c = tid; c < n_px * 16; c += 256) {
        int pix = c >> 4, c8 = (c & 15) * 8;
        *(uint4*)&sA[pix * 136 + c8] =
            *(const uint4*)&yin[((size_t)roi * 196 + base_px + pix) * 256 + kh * 128 + c8];
      }
    }
    __syncthreads();

    for (int t = 0; t < 9; t++) {
      int tap = t + rot; if (tap >= 9) tap -= 9;
      const int dy = tap / 3 - 1, dx = tap % 3 - 1;
      int offs[7];
#pragma unroll
      for (int mt = 0; mt < 7; mt++) {
        int ny = py[mt] + dy, nx = px[mt] + dx;
        bool v = ((u32)ny < 14u) && ((u32)nx < 14u);
        offs[mt] = v ? ((ny * 14 + nx) - base_px) * 136 : ZP;
      }
#pragma unroll
      for (int kk = 0; kk < 4; kk++) {
        // ---- next pipeline step's (tap, kh, kk) for the B prefetch ----
        int nt = t, nh = kh, nk = kk + 1;
        if (kk == 3) {
          nk = 0; nt = t + 1;
          if (nt == 9) {
            if (kh == 0) { nt = 0; nh = 1; }          // cross into half 1
            else         { nt = 8; nh = 1; nk = 3; }  // very last: benign reload
          }
        }
        int ntap = nt + rot; if (ntap >= 9) ntap -= 9;
        const u16* wn = wb + (ntap * 8 + nh * 4 + nk) * 8192;
        if ((kk & 1) == 0) {
#pragma unroll
          for (int nf = 0; nf < 4; nf++) b1[nf] = *(const f16x8*)&wn[nf * 512];
#pragma unroll
          for (int mt = 0; mt < 7; mt++) {
            f16x8 a = *(const f16x8*)&sA[offs[mt] + kk * 32 + q * 8];
#pragma unroll
            for (int nf = 0; nf < 4; nf++)
              acc[mt][nf] = __builtin_amdgcn_mfma_f32_16x16x32_f16(a, b0[nf], acc[mt][nf], 0, 0, 0);
          }
        } else {
#pragma unroll
          for (int nf = 0; nf < 4; nf++) b0[nf] = *(const f16x8*)&wn[nf * 512];
#pragma unroll
          for (int mt = 0; mt < 7; mt++) {
            f16x8 a = *(const f16x8*)&sA[offs[mt] + kk * 32 + q * 8];
#pragma unroll
            for (int nf = 0; nf < 4; nf++)
              acc[mt][nf] = __builtin_amdgcn_mfma_f32_16x16x32_f16(a, b1[nf], acc[mt][nf], 0, 0, 0);
          }
        }
      }
    }
  }

  float bias[4];
#pragma unroll
  for (int nf = 0; nf < 4; nf++) bias[nf] = bc[layer * 256 + (w * 4 + nf) * 16 + r];
#pragma unroll
  for (int mt = 0; mt < 7; mt++) {
#pragma unroll
    for (int jj = 0; jj < 4; jj++) {
      int p = mbase + mt * 16 + q * 4 + jj;   // C/D: row = q*4+reg, col = r
      if (p < 196) {
#pragma unroll
        for (int nf = 0; nf < 4; nf++) {
          float v = acc[mt][nf][jj] + bias[nf];
          v = fmaxf(v, 0.f);
          out[((size_t)roi * 196 + p) * 256 + (w * 4 + nf) * 16 + r] = f2h(v);
        }
      }
    }
  }
}

// ---------------------------------------------------------------------------
// Fused transpose-conv (2x2 s2 VALID, per-quadrant 1x1 GEMM) + relu + 1x1 mask.
// Block = (roi, quadrant ab, M-half). Phase 1: T = relu(y4 x WtP[ab] + bt)
// -> LDS tile [112][264] fp16. Phase 2: out = T x Wm + bm (N=80 = 5 tiles).
// This round: windowed staging (no halo for 1x1: stage only own 112/84 px)
// + double-buffered B prefetch in phase 1.
// ---------------------------------------------------------------------------
__global__ __launch_bounds__(256, 2)
void tail_fused(const u16* __restrict__ y4, const u16* __restrict__ WtP,
                const u16* __restrict__ WmP, const float* __restrict__ bt,
                const float* __restrict__ bm, float* __restrict__ out) {
  __shared__ u16 sA[112 * 264 + 128];
  const int ZP = 112 * 264;
  const int tid = threadIdx.x;
  const int w = tid >> 6, lane = tid & 63, q = lane >> 4, r = lane & 15;
  const int roi = blockIdx.x, ab = blockIdx.y, mbase = blockIdx.z * 112;
  const int n_px = mbase ? 84 : 112;
  if (tid < 64) ((u32*)(sA + ZP))[tid] = 0u;

  int offs[7];
#pragma unroll
  for (int mt = 0; mt < 7; mt++) {
    int p = mbase + mt * 16 + r;
    offs[mt] = (p < 196) ? (mt * 16 + r) * 136 : ZP;
  }
  f32x4 acc[7][4];
#pragma unroll
  for (int mt = 0; mt < 7; mt++)
#pragma unroll
    for (int nf = 0; nf < 4; nf++) acc[mt][nf] = (f32x4){0.f, 0.f, 0.f, 0.f};

  const u16* wt = WtP + ab * 65536 + (w * 4) * 512 + lane * 8;  // off: kc*8192+nf*512
  f16x8 b0[4], b1[4];
#pragma unroll
  for (int nf = 0; nf < 4; nf++) b0[nf] = *(const f16x8*)&wt[nf * 512];  // kc=0

  for (int kh = 0; kh < 2; kh++) {
    if (kh) __syncthreads();
    for (int c = tid; c < n_px * 16; c += 256) {
      int pix = c >> 4, c8 = (c & 15) * 8;
      *(uint4*)&sA[pix * 136 + c8] =
          *(const uint4*)&y4[((size_t)roi * 196 + mbase + pix) * 256 + kh * 128 + c8];
    }
    __syncthreads();
#pragma unroll
    for (int kk = 0; kk < 4; kk++) {
      int nc_ = kh * 4 + kk + 1; if (nc_ > 7) nc_ = 7;   // next kc (clamped)
      const u16* wn = wt + nc_ * 8192;
      if ((kk & 1) == 0) {
#pragma unroll
        for (int nf = 0; nf < 4; nf++) b1[nf] = *(const f16x8*)&wn[nf * 512];
#pragma unroll
        for (int mt = 0; mt < 7; mt++) {
          f16x8 a = *(const f16x8*)&sA[offs[mt] + kk * 32 + q * 8];
#pragma unroll
          for (int nf = 0; nf < 4; nf++)
            acc[mt][nf] = __builtin_amdgcn_mfma_f32_16x16x32_f16(a, b0[nf], acc[mt][nf], 0, 0, 0);
        }
      } else {
#pragma unroll
        for (int nf = 0; nf < 4; nf++) b0[nf] = *(const f16x8*)&wn[nf * 512];
#pragma unroll
        for (int mt = 0; mt < 7; mt++) {
          f16x8 a = *(const f16x8*)&sA[offs[mt] + kk * 32 + q * 8];
#pragma unroll
          for (int nf = 0; nf < 4; nf++)
            acc[mt][nf] = __builtin_amdgcn_mfma_f32_16x16x32_f16(a, b1[nf], acc[mt][nf], 0, 0, 0);
        }
      }
    }
  }

  __syncthreads();                           // all K-loop LDS reads done
  float btv[4];
#pragma unroll
  for (int nf = 0; nf < 4; nf++) btv[nf] = bt[(w * 4 + nf) * 16 + r];
#pragma unroll
  for (int mt = 0; mt < 7; mt++) {
#pragma unroll
    for (int jj = 0; jj < 4; jj++) {
      int row = mt * 16 + q * 4 + jj;        // 0..111
#pragma unroll
      for (int nf = 0; nf < 4; nf++) {
        float v = fmaxf(acc[mt][nf][jj] + btv[nf], 0.f);
        sA[row * 264 + (w * 4 + nf) * 16 + r] = f2h(v);
      }
    }
  }
  __syncthreads();

  float bmv[5];
#pragma unroll
  for (int nt = 0; nt < 5; nt++) bmv[nt] = bm[nt * 16 + r];
  const int a_ = ab >> 1, b_ = ab & 1;
  for (int tt = w; tt < 7; tt += 4) {
    f32x4 a2[5];
#pragma unroll
    for (int nt = 0; nt < 5; nt++) a2[nt] = (f32x4){0.f, 0.f, 0.f, 0.f};
#pragma unroll
    for (int kc = 0; kc < 8; kc++) {
      f16x8 af = *(const f16x8*)&sA[(tt * 16 + r) * 264 + kc * 32 + q * 8];
#pragma unroll
      for (int nt = 0; nt < 5; nt++) {
        f16x8 bw = *(const f16x8*)&WmP[((kc * 5 + nt) * 64 + lane) * 8];
        a2[nt] = __builtin_amdgcn_mfma_f32_16x16x32_f16(af, bw, a2[nt], 0, 0, 0);
      }
    }
#pragma unroll
    for (int jj = 0; jj < 4; jj++) {
      int row = tt * 16 + q * 4 + jj;
      int p = mbase + row;
      if (p < 196) {
        int y = p / 14, x = p % 14;
        size_t base = (size_t)roi * 62720 + (2 * y + a_) * 2240 + (2 * x + b_) * 80;
#pragma unroll
        for (int nt = 0; nt < 5; nt++) out[base + nt * 16 + r] = a2[nt][jj] + bmv[nt];
      }
    }
  }
}

// ---------------------------------------------------------------------------
extern "C" void kernel_launch(void* const* d_in, const int* in_sizes, int n_in,
                              void* d_out, int out_size, void* d_ws, size_t ws_size,
                              hipStream_t stream) {
  const float* x  = (const float*)d_in[0];
  const float* Wc = (const float*)d_in[1];
  const float* bc = (const float*)d_in[2];
  const float* Wt = (const float*)d_in[3];
  const float* bt = (const float*)d_in[4];
  const float* Wm = (const float*)d_in[5];
  const float* bm = (const float*)d_in[6];
  float* out = (float*)d_out;

  char* ws = (char*)d_ws;
  u16* WbP = (u16*)(ws);                         // 4,718,592 B
  u16* WtP = (u16*)(ws + 4718592);               //   524,288 B
  u16* WmP = (u16*)(ws + 5242880);               //    40,960 B
  u16* yA  = (u16*)(ws + 6291456);               // 102,760,448 B
  u16* yB  = (u16*)(ws + 6291456 + 102760448);   // 102,760,448 B  (total ~212 MB)

  prep_weights<<<1290, 256, 0, stream>>>(Wc, Wt, Wm, WbP, WtP, WmP);

  dim3 cg(1024, 2);
  conv_layer<true ><<<cg, 256, 0, stream>>>(x,  WbP, bc, yA, 0);
  conv_layer<false><<<cg, 256, 0, stream>>>(yA, WbP, bc, yB, 1);
  conv_layer<false><<<cg, 256, 0, stream>>>(yB, WbP, bc, yA, 2);
  conv_layer<false><<<cg, 256, 0, stream>>>(yA, WbP, bc, yB, 3);

  tail_fused<<<dim3(1024, 4, 2), 256, 0, stream>>>(yB, WtP, WmP, bt, bm, out);
}